// Round 14
// baseline (202.410 us; speedup 1.0000x reference)
//
#include <hip/hip_runtime.h>
#include <math.h>

constexpr int CIN = 128, CHID = 64, COUT = 16;

// ---------------------------------------------------------------------------
// Edge-index dtype detection.
// ---------------------------------------------------------------------------
__global__ void detect_kernel(const int* __restrict__ e, int* __restrict__ flag) {
    int v = e[2 * threadIdx.x + 1];
    unsigned long long b = __ballot(v == 0);
    if (threadIdx.x == 0) flag[0] = (b == 0xFFFFFFFFFFFFFFFFULL) ? 1 : 0;
}

// convert to int32 src/dst + histogram of dst (int atomics)
__global__ void convert_hist(const int* __restrict__ e, int E,
                             const int* __restrict__ flag,
                             int* __restrict__ srcI, int* __restrict__ dstI,
                             int* __restrict__ counts) {
    int is64 = flag[0];
    int stride = gridDim.x * blockDim.x;
    for (int t = blockIdx.x * blockDim.x + threadIdx.x; t < E; t += stride) {
        int s, d;
        if (is64) { s = e[2 * t]; d = e[2 * (E + t)]; }
        else      { s = e[t];     d = e[E + t];       }
        srcI[t] = s;
        dstI[t] = d;
        atomicAdd(&counts[d], 1);
    }
}

// ---------------------------------------------------------------------------
// Multi-block exclusive scan of counts[N] -> rowptr[N+1] (+ cursor copy).
// ---------------------------------------------------------------------------
__global__ __launch_bounds__(256)
void scan_partials(const int* __restrict__ counts, int N, int* __restrict__ blocksum) {
    __shared__ int red[256];
    const int tid = threadIdx.x;
    const int base = blockIdx.x * 1024 + tid * 4;
    int s = 0;
#pragma unroll
    for (int i = 0; i < 4; ++i) {
        int idx = base + i;
        if (idx < N) s += counts[idx];
    }
    red[tid] = s;
    __syncthreads();
    for (int d = 128; d > 0; d >>= 1) {
        if (tid < d) red[tid] += red[tid + d];
        __syncthreads();
    }
    if (tid == 0) blocksum[blockIdx.x] = red[0];
}

__global__ __launch_bounds__(1024)
void scan_blocksums(const int* __restrict__ blocksum, int NB, int* __restrict__ blockoff) {
    __shared__ int part[1024];
    const int tid = threadIdx.x;
    part[tid] = (tid < NB) ? blocksum[tid] : 0;
    __syncthreads();
    for (int d = 1; d < 1024; d <<= 1) {
        int v = (tid >= d) ? part[tid - d] : 0;
        __syncthreads();
        part[tid] += v;
        __syncthreads();
    }
    if (tid < NB) blockoff[tid] = (tid == 0) ? 0 : part[tid - 1];
}

__global__ __launch_bounds__(256)
void scan_apply(const int* __restrict__ counts, int N, const int* __restrict__ blockoff,
                int* __restrict__ rowptr, int* __restrict__ cursor) {
    __shared__ int part[256];
    const int tid = threadIdx.x;
    const int base = blockIdx.x * 1024 + tid * 4;
    int c[4];
    int s = 0;
#pragma unroll
    for (int i = 0; i < 4; ++i) {
        int idx = base + i;
        c[i] = (idx < N) ? counts[idx] : 0;
        s += c[i];
    }
    part[tid] = s;
    __syncthreads();
    for (int d = 1; d < 256; d <<= 1) {
        int v = (tid >= d) ? part[tid - d] : 0;
        __syncthreads();
        part[tid] += v;
        __syncthreads();
    }
    int prefix = blockoff[blockIdx.x] + ((tid == 0) ? 0 : part[tid - 1]);
#pragma unroll
    for (int i = 0; i < 4; ++i) {
        int idx = base + i;
        if (idx < N) {
            rowptr[idx] = prefix;
            cursor[idx] = prefix;
            prefix += c[i];
            if (idx == N - 1) rowptr[N] = prefix;
        }
    }
}

// bucket-fill: edgesrc grouped by dst
__global__ void fill_kernel(const int* __restrict__ srcI, const int* __restrict__ dstI,
                            int E, int* __restrict__ cursor, int* __restrict__ edgesrc) {
    int stride = gridDim.x * blockDim.x;
    for (int t = blockIdx.x * blockDim.x + threadIdx.x; t < E; t += stride) {
        int p = atomicAdd(&cursor[dstI[t]], 1);
        edgesrc[p] = srcI[t];
    }
}

// ---------------------------------------------------------------------------
// L1 GEMM: 4 nodes x (4 root + 4 rel) outputs per thread (R13, ~61us —
// tied with best; GEMM lane closed after 8 structural attempts).
// ---------------------------------------------------------------------------
template<int K, int KT, int OH, int NSLOT, int MBLK>
__global__ __launch_bounds__(256)
void gemm_dual48(const float* __restrict__ X, int N,
                 const float* __restrict__ Wa, const float* __restrict__ Wb,
                 const float* __restrict__ bias,
                 float* __restrict__ Da, float* __restrict__ Db) {
    constexpr int O = 2 * OH;            // 128
    constexpr int OG = OH / 4;           // 16
    constexpr int TILE = NSLOT * MBLK;   // 64
    constexpr int BLOCK = OG * NSLOT;    // 256
    constexpr int PADKT = KT + 4;        // 36
    static_assert(BLOCK == 256, "block size mismatch");

    __shared__ float wT[KT * O];                           // row k: [Wa | Wb]
    __shared__ float xs[TILE * PADKT + (TILE / 8) * 4];    // group-padded
    const int tid = threadIdx.x;

    const int og = tid % OG;
    const int slot = tid / OG;
    const int o4 = og * 4;
    const float4 bv = *(const float4*)&bias[o4];

    const int n0 = blockIdx.x * TILE;
    const int node0 = slot * MBLK;
    const int xbase = node0 * PADKT + (node0 >> 3) * 4;

    float4 accA[MBLK], accB[MBLK];
#pragma unroll
    for (int i = 0; i < MBLK; ++i) {
        accA[i] = make_float4(0.f, 0.f, 0.f, 0.f);
        accB[i] = make_float4(0.f, 0.f, 0.f, 0.f);
    }

    for (int kt = 0; kt < K; kt += KT) {
        for (int i4 = tid; i4 < OH * (KT / 4); i4 += BLOCK) {
            int o = i4 % OH, kq = i4 / OH;
            float4 v = *(const float4*)&Wa[o * K + kt + kq * 4];
            wT[(4 * kq + 0) * O + o] = v.x;
            wT[(4 * kq + 1) * O + o] = v.y;
            wT[(4 * kq + 2) * O + o] = v.z;
            wT[(4 * kq + 3) * O + o] = v.w;
        }
        for (int i4 = tid; i4 < OH * (KT / 4); i4 += BLOCK) {
            int o = i4 % OH, kq = i4 / OH;
            float4 v = *(const float4*)&Wb[o * K + kt + kq * 4];
            wT[(4 * kq + 0) * O + OH + o] = v.x;
            wT[(4 * kq + 1) * O + OH + o] = v.y;
            wT[(4 * kq + 2) * O + OH + o] = v.z;
            wT[(4 * kq + 3) * O + OH + o] = v.w;
        }
        for (int i4 = tid; i4 < TILE * (KT / 4); i4 += BLOCK) {
            int node = i4 / (KT / 4), kq = i4 % (KT / 4);
            int n = n0 + node;
            float4 v = make_float4(0.f, 0.f, 0.f, 0.f);
            if (n < N) v = *(const float4*)&X[(size_t)n * K + kt + kq * 4];
            *(float4*)&xs[node * PADKT + (node >> 3) * 4 + kq * 4] = v;
        }
        __syncthreads();

#pragma unroll 2
        for (int kq = 0; kq < KT / 4; ++kq) {
            const float* wr0 = &wT[(4 * kq + 0) * O];
            const float* wr1 = &wT[(4 * kq + 1) * O];
            const float* wr2 = &wT[(4 * kq + 2) * O];
            const float* wr3 = &wT[(4 * kq + 3) * O];
            float4 wa0 = *(const float4*)&wr0[o4], wb0 = *(const float4*)&wr0[OH + o4];
            float4 wa1 = *(const float4*)&wr1[o4], wb1 = *(const float4*)&wr1[OH + o4];
            float4 wa2 = *(const float4*)&wr2[o4], wb2 = *(const float4*)&wr2[OH + o4];
            float4 wa3 = *(const float4*)&wr3[o4], wb3 = *(const float4*)&wr3[OH + o4];
#pragma unroll
            for (int i = 0; i < MBLK; ++i) {
                float4 xq = *(const float4*)&xs[xbase + i * PADKT + ((node0 + i) >> 3 != node0 >> 3 ? 4 : 0) + kq * 4];
                accA[i].x = fmaf(xq.x, wa0.x, accA[i].x);
                accA[i].y = fmaf(xq.x, wa0.y, accA[i].y);
                accA[i].z = fmaf(xq.x, wa0.z, accA[i].z);
                accA[i].w = fmaf(xq.x, wa0.w, accA[i].w);
                accB[i].x = fmaf(xq.x, wb0.x, accB[i].x);
                accB[i].y = fmaf(xq.x, wb0.y, accB[i].y);
                accB[i].z = fmaf(xq.x, wb0.z, accB[i].z);
                accB[i].w = fmaf(xq.x, wb0.w, accB[i].w);

                accA[i].x = fmaf(xq.y, wa1.x, accA[i].x);
                accA[i].y = fmaf(xq.y, wa1.y, accA[i].y);
                accA[i].z = fmaf(xq.y, wa1.z, accA[i].z);
                accA[i].w = fmaf(xq.y, wa1.w, accA[i].w);
                accB[i].x = fmaf(xq.y, wb1.x, accB[i].x);
                accB[i].y = fmaf(xq.y, wb1.y, accB[i].y);
                accB[i].z = fmaf(xq.y, wb1.z, accB[i].z);
                accB[i].w = fmaf(xq.y, wb1.w, accB[i].w);

                accA[i].x = fmaf(xq.z, wa2.x, accA[i].x);
                accA[i].y = fmaf(xq.z, wa2.y, accA[i].y);
                accA[i].z = fmaf(xq.z, wa2.z, accA[i].z);
                accA[i].w = fmaf(xq.z, wa2.w, accA[i].w);
                accB[i].x = fmaf(xq.z, wb2.x, accB[i].x);
                accB[i].y = fmaf(xq.z, wb2.y, accB[i].y);
                accB[i].z = fmaf(xq.z, wb2.z, accB[i].z);
                accB[i].w = fmaf(xq.z, wb2.w, accB[i].w);

                accA[i].x = fmaf(xq.w, wa3.x, accA[i].x);
                accA[i].y = fmaf(xq.w, wa3.y, accA[i].y);
                accA[i].z = fmaf(xq.w, wa3.z, accA[i].z);
                accA[i].w = fmaf(xq.w, wa3.w, accA[i].w);
                accB[i].x = fmaf(xq.w, wb3.x, accB[i].x);
                accB[i].y = fmaf(xq.w, wb3.y, accB[i].y);
                accB[i].z = fmaf(xq.w, wb3.z, accB[i].z);
                accB[i].w = fmaf(xq.w, wb3.w, accB[i].w);
            }
        }
        __syncthreads();
    }

#pragma unroll
    for (int i = 0; i < MBLK; ++i) {
        int n = n0 + node0 + i;
        if (n >= N) continue;
        float4 ra = accA[i];
        ra.x += bv.x; ra.y += bv.y; ra.z += bv.z; ra.w += bv.w;
        *(float4*)&Da[(size_t)n * OH + o4] = ra;
        *(float4*)&Db[(size_t)n * OH + o4] = accB[i];
    }
}

// ---------------------------------------------------------------------------
// Fused layer-2: stage h = relu(t0 + gather(t1)) into LDS, then dual GEMM
// T3 = h@W2root^T + b2, T2 = h@W2rel^T. Eliminates the materialized h
// (25.6MB write + 25.6MB read) and one launch. Gather staging: 16 threads
// per node read 256B-coalesced t1 rows (same pattern as the old standalone
// gather kernel). K=64 single pass.
// ---------------------------------------------------------------------------
template<int K, int OA, int OB, int NSLOT, int T>
__global__ __launch_bounds__(512)
void gemm2_fused(const float* __restrict__ T0, const float* __restrict__ T1, int N,
                 const int* __restrict__ rowptr, const int* __restrict__ edgesrc,
                 const float* __restrict__ Wa, const float* __restrict__ Wb,
                 const float* __restrict__ bias,
                 float* __restrict__ Da, float* __restrict__ Db) {
    constexpr int O = OA + OB;           // 32
    constexpr int OG = O / 4;            // 8
    constexpr int TILE = NSLOT * T;      // 128
    constexpr int PADK = K + 4;          // 68
    constexpr int BLOCK = OG * NSLOT;    // 512
    static_assert(BLOCK == 512, "block size mismatch");
    static_assert(K == CHID, "single-pass K");

    __shared__ float wT[K * O];          // 8 KB
    __shared__ float xs[TILE * PADK];    // 34.8 KB
    const int tid = threadIdx.x;

    const int og = tid % OG;
    const int slot = tid / OG;
    const int o4 = og * 4;
    float4 bv = make_float4(0.f, 0.f, 0.f, 0.f);
    if (o4 < OA) bv = *(const float4*)&bias[o4];

    const int n0 = blockIdx.x * TILE;

    // --- stage weights (k-major) ---
    for (int i4 = tid; i4 < OA * (K / 4); i4 += BLOCK) {
        int o = i4 % OA, kq = i4 / OA;
        float4 v = *(const float4*)&Wa[o * K + kq * 4];
        wT[(4 * kq + 0) * O + o] = v.x;
        wT[(4 * kq + 1) * O + o] = v.y;
        wT[(4 * kq + 2) * O + o] = v.z;
        wT[(4 * kq + 3) * O + o] = v.w;
    }
    for (int i4 = tid; i4 < OB * (K / 4); i4 += BLOCK) {
        int o = i4 % OB, kq = i4 / OB;
        float4 v = *(const float4*)&Wb[o * K + kq * 4];
        wT[(4 * kq + 0) * O + OA + o] = v.x;
        wT[(4 * kq + 1) * O + OA + o] = v.y;
        wT[(4 * kq + 2) * O + OA + o] = v.z;
        wT[(4 * kq + 3) * O + OA + o] = v.w;
    }

    // --- stage h = relu(t0 + gather(t1)) : 16 threads per node ---
    {
        const int g = tid >> 4;      // 32 groups
        const int q = tid & 15;      // quad index within 64-wide row
        for (int node = g; node < TILE; node += 32) {
            int n = n0 + node;
            float4 h = make_float4(0.f, 0.f, 0.f, 0.f);
            if (n < N) {
                int beg = rowptr[n], end = rowptr[n + 1];
                float4 a0 = make_float4(0.f, 0.f, 0.f, 0.f);
                float4 a1 = make_float4(0.f, 0.f, 0.f, 0.f);
                int j = beg;
                for (; j + 1 < end; j += 2) {
                    int s0 = edgesrc[j];
                    int s1 = edgesrc[j + 1];
                    float4 v0 = *(const float4*)&T1[(size_t)s0 * K + q * 4];
                    float4 v1 = *(const float4*)&T1[(size_t)s1 * K + q * 4];
                    a0.x += v0.x; a0.y += v0.y; a0.z += v0.z; a0.w += v0.w;
                    a1.x += v1.x; a1.y += v1.y; a1.z += v1.z; a1.w += v1.w;
                }
                if (j < end) {
                    int s0 = edgesrc[j];
                    float4 v0 = *(const float4*)&T1[(size_t)s0 * K + q * 4];
                    a0.x += v0.x; a0.y += v0.y; a0.z += v0.z; a0.w += v0.w;
                }
                float4 t = *(const float4*)&T0[(size_t)n * K + q * 4];
                h.x = fmaxf(t.x + a0.x + a1.x, 0.f);
                h.y = fmaxf(t.y + a0.y + a1.y, 0.f);
                h.z = fmaxf(t.z + a0.z + a1.z, 0.f);
                h.w = fmaxf(t.w + a0.w + a1.w, 0.f);
            }
            *(float4*)&xs[node * PADK + q * 4] = h;
        }
    }
    __syncthreads();

    // --- dual GEMM compute (identical to gemm_dual inner, single K pass) ---
    float4 acc[T];
#pragma unroll
    for (int i = 0; i < T; ++i) acc[i] = make_float4(0.f, 0.f, 0.f, 0.f);

    const float* xrow = &xs[slot * T * PADK];
#pragma unroll 2
    for (int kq = 0; kq < K / 4; ++kq) {
        float4 w0 = *(const float4*)&wT[(4 * kq + 0) * O + o4];
        float4 w1 = *(const float4*)&wT[(4 * kq + 1) * O + o4];
        float4 w2 = *(const float4*)&wT[(4 * kq + 2) * O + o4];
        float4 w3 = *(const float4*)&wT[(4 * kq + 3) * O + o4];
#pragma unroll
        for (int i = 0; i < T; ++i) {
            float4 xq = *(const float4*)&xrow[i * PADK + kq * 4];
            acc[i].x = fmaf(xq.x, w0.x, acc[i].x);
            acc[i].y = fmaf(xq.x, w0.y, acc[i].y);
            acc[i].z = fmaf(xq.x, w0.z, acc[i].z);
            acc[i].w = fmaf(xq.x, w0.w, acc[i].w);
            acc[i].x = fmaf(xq.y, w1.x, acc[i].x);
            acc[i].y = fmaf(xq.y, w1.y, acc[i].y);
            acc[i].z = fmaf(xq.y, w1.z, acc[i].z);
            acc[i].w = fmaf(xq.y, w1.w, acc[i].w);
            acc[i].x = fmaf(xq.z, w2.x, acc[i].x);
            acc[i].y = fmaf(xq.z, w2.y, acc[i].y);
            acc[i].z = fmaf(xq.z, w2.z, acc[i].z);
            acc[i].w = fmaf(xq.z, w2.w, acc[i].w);
            acc[i].x = fmaf(xq.w, w3.x, acc[i].x);
            acc[i].y = fmaf(xq.w, w3.y, acc[i].y);
            acc[i].z = fmaf(xq.w, w3.z, acc[i].z);
            acc[i].w = fmaf(xq.w, w3.w, acc[i].w);
        }
    }

#pragma unroll
    for (int i = 0; i < T; ++i) {
        int n = n0 + slot * T + i;
        if (n >= N) continue;
        float4 r = acc[i];
        if (o4 < OA) {
            r.x += bv.x; r.y += bv.y; r.z += bv.z; r.w += bv.w;
            *(float4*)&Da[(size_t)n * OA + o4] = r;
        } else {
            *(float4*)&Db[(size_t)n * OB + (o4 - OA)] = r;
        }
    }
}

// ---------------------------------------------------------------------------
// CSR gather of t2 (width 16) + fused log_softmax(t3 + agg). 2-edge unroll.
// ---------------------------------------------------------------------------
__global__ void gather_lsm(const int* __restrict__ rowptr, const int* __restrict__ edgesrc,
                           const float* __restrict__ T3, const float* __restrict__ T2,
                           float* __restrict__ out, int N) {
    int idx = blockIdx.x * blockDim.x + threadIdx.x;
    int n = idx / 4, c = idx % 4;
    if (n >= N) return;
    int beg = rowptr[n], end = rowptr[n + 1];
    float4 acc0 = make_float4(0.f, 0.f, 0.f, 0.f);
    float4 acc1 = make_float4(0.f, 0.f, 0.f, 0.f);
    int j = beg;
    for (; j + 1 < end; j += 2) {
        int s0 = edgesrc[j];
        int s1 = edgesrc[j + 1];
        float4 v0 = *(const float4*)&T2[(size_t)s0 * 16 + c * 4];
        float4 v1 = *(const float4*)&T2[(size_t)s1 * 16 + c * 4];
        acc0.x += v0.x; acc0.y += v0.y; acc0.z += v0.z; acc0.w += v0.w;
        acc1.x += v1.x; acc1.y += v1.y; acc1.z += v1.z; acc1.w += v1.w;
    }
    if (j < end) {
        int s0 = edgesrc[j];
        float4 v0 = *(const float4*)&T2[(size_t)s0 * 16 + c * 4];
        acc0.x += v0.x; acc0.y += v0.y; acc0.z += v0.z; acc0.w += v0.w;
    }
    acc0.x += acc1.x; acc0.y += acc1.y; acc0.z += acc1.z; acc0.w += acc1.w;
    float4 t = *(const float4*)&T3[(size_t)n * 16 + c * 4];
    float4 v = make_float4(t.x + acc0.x, t.y + acc0.y, t.z + acc0.z, t.w + acc0.w);
    float m = fmaxf(fmaxf(v.x, v.y), fmaxf(v.z, v.w));
    for (int d = 1; d < 4; d <<= 1) m = fmaxf(m, __shfl_xor(m, d, 4));
    float s = expf(v.x - m) + expf(v.y - m) + expf(v.z - m) + expf(v.w - m);
    for (int d = 1; d < 4; d <<= 1) s += __shfl_xor(s, d, 4);
    float ls = m + logf(s);
    float4 r = make_float4(v.x - ls, v.y - ls, v.z - ls, v.w - ls);
    *(float4*)&out[(size_t)n * 16 + c * 4] = r;
}

extern "C" void kernel_launch(void* const* d_in, const int* in_sizes, int n_in,
                              void* d_out, int out_size, void* d_ws, size_t ws_size,
                              hipStream_t stream) {
    const float* X      = (const float*)d_in[0];
    const int*   EIDX   = (const int*)d_in[1];
    const float* W1REL  = (const float*)d_in[2];
    const float* W1ROOT = (const float*)d_in[3];
    const float* B1     = (const float*)d_in[4];
    const float* W2REL  = (const float*)d_in[5];
    const float* W2ROOT = (const float*)d_in[6];
    const float* B2     = (const float*)d_in[7];
    float* OUT = (float*)d_out;

    const int N = in_sizes[0] / CIN;   // 100000
    const int E = in_sizes[1] / 2;     // 640000
    const int NB = (N + 1023) / 1024;  // scan blocks

    char* wsb = (char*)d_ws;
    size_t off = 0;
    auto alloc = [&](size_t bytes) { void* p = wsb + off; off += (bytes + 255) & ~size_t(255); return p; };

    int* flag     = (int*)alloc(256);
    int* srcI     = (int*)alloc((size_t)E * 4);
    int* dstI     = (int*)alloc((size_t)E * 4);
    int* edgesrc  = (int*)alloc((size_t)E * 4);
    int* counts   = (int*)alloc((size_t)N * 4);
    int* rowptr   = (int*)alloc((size_t)(N + 1) * 4);
    int* cursor   = (int*)alloc((size_t)N * 4);
    int* blocksum = (int*)alloc((size_t)NB * 4);
    int* blockoff = (int*)alloc((size_t)NB * 4);
    float* A      = (float*)alloc((size_t)N * CHID * 4);  // t0
    float* Bt     = (float*)alloc((size_t)N * CHID * 4);  // t1
    float* T3     = (float*)alloc((size_t)N * COUT * 4);  // h@W2root + b2
    float* T2     = (float*)alloc((size_t)N * COUT * 4);  // h@W2rel
    if (off > ws_size) return;

    hipMemsetAsync(counts, 0, (size_t)N * 4, stream);

    detect_kernel<<<1, 64, 0, stream>>>(EIDX, flag);
    convert_hist<<<1024, 256, 0, stream>>>(EIDX, E, flag, srcI, dstI, counts);
    scan_partials<<<NB, 256, 0, stream>>>(counts, N, blocksum);
    scan_blocksums<<<1, 1024, 0, stream>>>(blocksum, NB, blockoff);
    scan_apply<<<NB, 256, 0, stream>>>(counts, N, blockoff, rowptr, cursor);
    fill_kernel<<<1024, 256, 0, stream>>>(srcI, dstI, E, cursor, edgesrc);

    // layer 1: A = X@W1root^T + b1 (t0), Bt = X@W1rel^T (t1)
    {
        constexpr int TILE = 16 * 4;   // NSLOT=16, MBLK=4
        int grid = (N + TILE - 1) / TILE;
        gemm_dual48<128, 32, 64, 16, 4><<<grid, 256, 0, stream>>>(X, N, W1ROOT, W1REL, B1, A, Bt);
    }

    // fused layer 2: h = relu(t0 + gather(t1)) staged in LDS;
    // T3 = h@W2root^T + b2, T2 = h@W2rel^T
    {
        constexpr int TILE = 64 * 2;   // NSLOT=64, T=2
        int grid = (N + TILE - 1) / TILE;
        gemm2_fused<64, 16, 16, 64, 2><<<grid, 512, 0, stream>>>(
            A, Bt, N, rowptr, edgesrc, W2ROOT, W2REL, B2, T3, T2);
    }

    // out = log_softmax(t3 + gather(t2))
    {
        int threads = N * 4;
        gather_lsm<<<(threads + 255) / 256, 256, 0, stream>>>(rowptr, edgesrc, T3, T2, OUT, N);
    }
}

// Round 15
// 190.184 us; speedup vs baseline: 1.0643x; 1.0643x over previous
//
#include <hip/hip_runtime.h>
#include <math.h>

constexpr int CIN = 128, CHID = 64, COUT = 16;

// ---------------------------------------------------------------------------
// Convert edges to int32 src/dst + histogram of dst (int atomics).
// Edge-dtype detection inlined (R15): wave 0 of every block ballots the first
// 64 odd int32 words -- all-zero <=> raw little-endian int64 (ids < 2^31).
// Deterministic and identical across blocks; removes the 1-block detect
// kernel + its graph-node gap.
// ---------------------------------------------------------------------------
__global__ void convert_hist(const int* __restrict__ e, int E,
                             int* __restrict__ srcI, int* __restrict__ dstI,
                             int* __restrict__ counts) {
    __shared__ int s_is64;
    const int tid = threadIdx.x;
    if (tid < 64) {
        int v = e[2 * tid + 1];
        unsigned long long b = __ballot(v == 0);
        if (tid == 0) s_is64 = (b == 0xFFFFFFFFFFFFFFFFULL) ? 1 : 0;
    }
    __syncthreads();
    const int is64 = s_is64;
    int stride = gridDim.x * blockDim.x;
    for (int t = blockIdx.x * blockDim.x + tid; t < E; t += stride) {
        int s, d;
        if (is64) { s = e[2 * t]; d = e[2 * (E + t)]; }
        else      { s = e[t];     d = e[E + t];       }
        srcI[t] = s;
        dstI[t] = d;
        atomicAdd(&counts[d], 1);
    }
}

// ---------------------------------------------------------------------------
// Scan pass A: per-block (1024-elem) partial sums of counts.
// ---------------------------------------------------------------------------
__global__ __launch_bounds__(256)
void scan_partials(const int* __restrict__ counts, int N, int* __restrict__ blocksum) {
    __shared__ int red[256];
    const int tid = threadIdx.x;
    const int base = blockIdx.x * 1024 + tid * 4;
    int s = 0;
#pragma unroll
    for (int i = 0; i < 4; ++i) {
        int idx = base + i;
        if (idx < N) s += counts[idx];
    }
    red[tid] = s;
    __syncthreads();
    for (int d = 128; d > 0; d >>= 1) {
        if (tid < d) red[tid] += red[tid + d];
        __syncthreads();
    }
    if (tid == 0) blocksum[blockIdx.x] = red[0];
}

// ---------------------------------------------------------------------------
// Scan pass B (merged, R15): each block redundantly scans the <=256 blocksums
// in LDS (8 Hillis-Steele steps) to get its own offset, then does its local
// scan + writes rowptr/cursor. Eliminates the 1-block scan_blocksums kernel.
// ---------------------------------------------------------------------------
__global__ __launch_bounds__(256)
void scan_apply(const int* __restrict__ counts, int N,
                const int* __restrict__ blocksum, int NB,
                int* __restrict__ rowptr, int* __restrict__ cursor) {
    __shared__ int bs[256];
    __shared__ int part[256];
    const int tid = threadIdx.x;

    // scan blocksums (NB <= 256 for N <= 262144)
    bs[tid] = (tid < NB) ? blocksum[tid] : 0;
    __syncthreads();
    for (int d = 1; d < 256; d <<= 1) {
        int v = (tid >= d) ? bs[tid - d] : 0;
        __syncthreads();
        bs[tid] += v;
        __syncthreads();
    }
    const int blockoff = (blockIdx.x == 0) ? 0 : bs[blockIdx.x - 1];

    const int base = blockIdx.x * 1024 + tid * 4;
    int c[4];
    int s = 0;
#pragma unroll
    for (int i = 0; i < 4; ++i) {
        int idx = base + i;
        c[i] = (idx < N) ? counts[idx] : 0;
        s += c[i];
    }
    part[tid] = s;
    __syncthreads();
    for (int d = 1; d < 256; d <<= 1) {
        int v = (tid >= d) ? part[tid - d] : 0;
        __syncthreads();
        part[tid] += v;
        __syncthreads();
    }
    int prefix = blockoff + ((tid == 0) ? 0 : part[tid - 1]);
#pragma unroll
    for (int i = 0; i < 4; ++i) {
        int idx = base + i;
        if (idx < N) {
            rowptr[idx] = prefix;
            cursor[idx] = prefix;
            prefix += c[i];
            if (idx == N - 1) rowptr[N] = prefix;
        }
    }
}

// bucket-fill: edgesrc grouped by dst
__global__ void fill_kernel(const int* __restrict__ srcI, const int* __restrict__ dstI,
                            int E, int* __restrict__ cursor, int* __restrict__ edgesrc) {
    int stride = gridDim.x * blockDim.x;
    for (int t = blockIdx.x * blockDim.x + threadIdx.x; t < E; t += stride) {
        int p = atomicAdd(&cursor[dstI[t]], 1);
        edgesrc[p] = srcI[t];
    }
}

// ---------------------------------------------------------------------------
// L1 GEMM: 4 nodes x (4 root + 4 rel) outputs per thread (R13 config, ~60us;
// GEMM lane closed -- 8 structural attempts all floor at ~60-62us).
// ---------------------------------------------------------------------------
template<int K, int KT, int OH, int NSLOT, int MBLK>
__global__ __launch_bounds__(256)
void gemm_dual48(const float* __restrict__ X, int N,
                 const float* __restrict__ Wa, const float* __restrict__ Wb,
                 const float* __restrict__ bias,
                 float* __restrict__ Da, float* __restrict__ Db) {
    constexpr int O = 2 * OH;            // 128
    constexpr int OG = OH / 4;           // 16
    constexpr int TILE = NSLOT * MBLK;   // 64
    constexpr int BLOCK = OG * NSLOT;    // 256
    constexpr int PADKT = KT + 4;        // 36
    static_assert(BLOCK == 256, "block size mismatch");

    __shared__ float wT[KT * O];                           // row k: [Wa | Wb]
    __shared__ float xs[TILE * PADKT + (TILE / 8) * 4];    // group-padded
    const int tid = threadIdx.x;

    const int og = tid % OG;
    const int slot = tid / OG;
    const int o4 = og * 4;
    const float4 bv = *(const float4*)&bias[o4];

    const int n0 = blockIdx.x * TILE;
    const int node0 = slot * MBLK;
    const int xbase = node0 * PADKT + (node0 >> 3) * 4;

    float4 accA[MBLK], accB[MBLK];
#pragma unroll
    for (int i = 0; i < MBLK; ++i) {
        accA[i] = make_float4(0.f, 0.f, 0.f, 0.f);
        accB[i] = make_float4(0.f, 0.f, 0.f, 0.f);
    }

    for (int kt = 0; kt < K; kt += KT) {
        for (int i4 = tid; i4 < OH * (KT / 4); i4 += BLOCK) {
            int o = i4 % OH, kq = i4 / OH;
            float4 v = *(const float4*)&Wa[o * K + kt + kq * 4];
            wT[(4 * kq + 0) * O + o] = v.x;
            wT[(4 * kq + 1) * O + o] = v.y;
            wT[(4 * kq + 2) * O + o] = v.z;
            wT[(4 * kq + 3) * O + o] = v.w;
        }
        for (int i4 = tid; i4 < OH * (KT / 4); i4 += BLOCK) {
            int o = i4 % OH, kq = i4 / OH;
            float4 v = *(const float4*)&Wb[o * K + kt + kq * 4];
            wT[(4 * kq + 0) * O + OH + o] = v.x;
            wT[(4 * kq + 1) * O + OH + o] = v.y;
            wT[(4 * kq + 2) * O + OH + o] = v.z;
            wT[(4 * kq + 3) * O + OH + o] = v.w;
        }
        for (int i4 = tid; i4 < TILE * (KT / 4); i4 += BLOCK) {
            int node = i4 / (KT / 4), kq = i4 % (KT / 4);
            int n = n0 + node;
            float4 v = make_float4(0.f, 0.f, 0.f, 0.f);
            if (n < N) v = *(const float4*)&X[(size_t)n * K + kt + kq * 4];
            *(float4*)&xs[node * PADKT + (node >> 3) * 4 + kq * 4] = v;
        }
        __syncthreads();

#pragma unroll 2
        for (int kq = 0; kq < KT / 4; ++kq) {
            const float* wr0 = &wT[(4 * kq + 0) * O];
            const float* wr1 = &wT[(4 * kq + 1) * O];
            const float* wr2 = &wT[(4 * kq + 2) * O];
            const float* wr3 = &wT[(4 * kq + 3) * O];
            float4 wa0 = *(const float4*)&wr0[o4], wb0 = *(const float4*)&wr0[OH + o4];
            float4 wa1 = *(const float4*)&wr1[o4], wb1 = *(const float4*)&wr1[OH + o4];
            float4 wa2 = *(const float4*)&wr2[o4], wb2 = *(const float4*)&wr2[OH + o4];
            float4 wa3 = *(const float4*)&wr3[o4], wb3 = *(const float4*)&wr3[OH + o4];
#pragma unroll
            for (int i = 0; i < MBLK; ++i) {
                float4 xq = *(const float4*)&xs[xbase + i * PADKT + ((node0 + i) >> 3 != node0 >> 3 ? 4 : 0) + kq * 4];
                accA[i].x = fmaf(xq.x, wa0.x, accA[i].x);
                accA[i].y = fmaf(xq.x, wa0.y, accA[i].y);
                accA[i].z = fmaf(xq.x, wa0.z, accA[i].z);
                accA[i].w = fmaf(xq.x, wa0.w, accA[i].w);
                accB[i].x = fmaf(xq.x, wb0.x, accB[i].x);
                accB[i].y = fmaf(xq.x, wb0.y, accB[i].y);
                accB[i].z = fmaf(xq.x, wb0.z, accB[i].z);
                accB[i].w = fmaf(xq.x, wb0.w, accB[i].w);

                accA[i].x = fmaf(xq.y, wa1.x, accA[i].x);
                accA[i].y = fmaf(xq.y, wa1.y, accA[i].y);
                accA[i].z = fmaf(xq.y, wa1.z, accA[i].z);
                accA[i].w = fmaf(xq.y, wa1.w, accA[i].w);
                accB[i].x = fmaf(xq.y, wb1.x, accB[i].x);
                accB[i].y = fmaf(xq.y, wb1.y, accB[i].y);
                accB[i].z = fmaf(xq.y, wb1.z, accB[i].z);
                accB[i].w = fmaf(xq.y, wb1.w, accB[i].w);

                accA[i].x = fmaf(xq.z, wa2.x, accA[i].x);
                accA[i].y = fmaf(xq.z, wa2.y, accA[i].y);
                accA[i].z = fmaf(xq.z, wa2.z, accA[i].z);
                accA[i].w = fmaf(xq.z, wa2.w, accA[i].w);
                accB[i].x = fmaf(xq.z, wb2.x, accB[i].x);
                accB[i].y = fmaf(xq.z, wb2.y, accB[i].y);
                accB[i].z = fmaf(xq.z, wb2.z, accB[i].z);
                accB[i].w = fmaf(xq.z, wb2.w, accB[i].w);

                accA[i].x = fmaf(xq.w, wa3.x, accA[i].x);
                accA[i].y = fmaf(xq.w, wa3.y, accA[i].y);
                accA[i].z = fmaf(xq.w, wa3.z, accA[i].z);
                accA[i].w = fmaf(xq.w, wa3.w, accA[i].w);
                accB[i].x = fmaf(xq.w, wb3.x, accB[i].x);
                accB[i].y = fmaf(xq.w, wb3.y, accB[i].y);
                accB[i].z = fmaf(xq.w, wb3.z, accB[i].z);
                accB[i].w = fmaf(xq.w, wb3.w, accB[i].w);
            }
        }
        __syncthreads();
    }

#pragma unroll
    for (int i = 0; i < MBLK; ++i) {
        int n = n0 + node0 + i;
        if (n >= N) continue;
        float4 ra = accA[i];
        ra.x += bv.x; ra.y += bv.y; ra.z += bv.z; ra.w += bv.w;
        *(float4*)&Da[(size_t)n * OH + o4] = ra;
        *(float4*)&Db[(size_t)n * OH + o4] = accB[i];
    }
}

// ---------------------------------------------------------------------------
// Dual-output GEMM (4x4 blocking) -- layer 2.
// ---------------------------------------------------------------------------
template<int K, int KT, int OA, int OB, int NSLOT, int T>
__global__ __launch_bounds__(512, 6)
void gemm_dual(const float* __restrict__ X, int N,
               const float* __restrict__ Wa, const float* __restrict__ Wb,
               const float* __restrict__ bias,
               float* __restrict__ Da, float* __restrict__ Db) {
    constexpr int O = OA + OB;
    constexpr int OG = O / 4;
    constexpr int TILE = NSLOT * T;
    constexpr int PADKT = KT + 4;
    constexpr int BLOCK = OG * NSLOT;
    static_assert(BLOCK == 512, "block size mismatch");

    __shared__ float wT[KT * O];
    __shared__ float xs[TILE * PADKT];
    const int tid = threadIdx.x;

    const int og = tid % OG;
    const int slot = tid / OG;
    const int o4 = og * 4;
    float4 bv = make_float4(0.f, 0.f, 0.f, 0.f);
    if (o4 < OA) bv = *(const float4*)&bias[o4];

    const int n0 = blockIdx.x * TILE;

    float4 acc[T];
#pragma unroll
    for (int i = 0; i < T; ++i) acc[i] = make_float4(0.f, 0.f, 0.f, 0.f);

    for (int kt = 0; kt < K; kt += KT) {
        for (int i4 = tid; i4 < OA * (KT / 4); i4 += BLOCK) {
            int o = i4 % OA, kq = i4 / OA;
            float4 v = *(const float4*)&Wa[o * K + kt + kq * 4];
            wT[(4 * kq + 0) * O + o] = v.x;
            wT[(4 * kq + 1) * O + o] = v.y;
            wT[(4 * kq + 2) * O + o] = v.z;
            wT[(4 * kq + 3) * O + o] = v.w;
        }
        for (int i4 = tid; i4 < OB * (KT / 4); i4 += BLOCK) {
            int o = i4 % OB, kq = i4 / OB;
            float4 v = *(const float4*)&Wb[o * K + kt + kq * 4];
            wT[(4 * kq + 0) * O + OA + o] = v.x;
            wT[(4 * kq + 1) * O + OA + o] = v.y;
            wT[(4 * kq + 2) * O + OA + o] = v.z;
            wT[(4 * kq + 3) * O + OA + o] = v.w;
        }
        for (int i4 = tid; i4 < TILE * (KT / 4); i4 += BLOCK) {
            int node = i4 / (KT / 4), kq = i4 % (KT / 4);
            int n = n0 + node;
            float4 v = make_float4(0.f, 0.f, 0.f, 0.f);
            if (n < N) v = *(const float4*)&X[(size_t)n * K + kt + kq * 4];
            *(float4*)&xs[node * PADKT + kq * 4] = v;
        }
        __syncthreads();

        const float* xrow = &xs[slot * T * PADKT];
#pragma unroll 2
        for (int kq = 0; kq < KT / 4; ++kq) {
            float4 w0 = *(const float4*)&wT[(4 * kq + 0) * O + o4];
            float4 w1 = *(const float4*)&wT[(4 * kq + 1) * O + o4];
            float4 w2 = *(const float4*)&wT[(4 * kq + 2) * O + o4];
            float4 w3 = *(const float4*)&wT[(4 * kq + 3) * O + o4];
#pragma unroll
            for (int i = 0; i < T; ++i) {
                float4 xq = *(const float4*)&xrow[i * PADKT + kq * 4];
                acc[i].x = fmaf(xq.x, w0.x, acc[i].x);
                acc[i].y = fmaf(xq.x, w0.y, acc[i].y);
                acc[i].z = fmaf(xq.x, w0.z, acc[i].z);
                acc[i].w = fmaf(xq.x, w0.w, acc[i].w);
                acc[i].x = fmaf(xq.y, w1.x, acc[i].x);
                acc[i].y = fmaf(xq.y, w1.y, acc[i].y);
                acc[i].z = fmaf(xq.y, w1.z, acc[i].z);
                acc[i].w = fmaf(xq.y, w1.w, acc[i].w);
                acc[i].x = fmaf(xq.z, w2.x, acc[i].x);
                acc[i].y = fmaf(xq.z, w2.y, acc[i].y);
                acc[i].z = fmaf(xq.z, w2.z, acc[i].z);
                acc[i].w = fmaf(xq.z, w2.w, acc[i].w);
                acc[i].x = fmaf(xq.w, w3.x, acc[i].x);
                acc[i].y = fmaf(xq.w, w3.y, acc[i].y);
                acc[i].z = fmaf(xq.w, w3.z, acc[i].z);
                acc[i].w = fmaf(xq.w, w3.w, acc[i].w);
            }
        }
        __syncthreads();
    }

#pragma unroll
    for (int i = 0; i < T; ++i) {
        int n = n0 + slot * T + i;
        if (n >= N) continue;
        float4 r = acc[i];
        if (o4 < OA) {
            r.x += bv.x; r.y += bv.y; r.z += bv.z; r.w += bv.w;
            *(float4*)&Da[(size_t)n * OA + o4] = r;
        } else {
            *(float4*)&Db[(size_t)n * OB + (o4 - OA)] = r;
        }
    }
}

// ---------------------------------------------------------------------------
// CSR gather + fused relu(t0 + agg), in place over A. 2-edge unroll.
// ---------------------------------------------------------------------------
__global__ void gather_relu64(const int* __restrict__ rowptr, const int* __restrict__ edgesrc,
                              const float* __restrict__ T1, float* __restrict__ A, int N) {
    constexpr int F = 64, Q = F / 4;
    int idx = blockIdx.x * blockDim.x + threadIdx.x;
    int n = idx / Q, q = idx % Q;
    if (n >= N) return;
    int beg = rowptr[n], end = rowptr[n + 1];
    float4 acc0 = make_float4(0.f, 0.f, 0.f, 0.f);
    float4 acc1 = make_float4(0.f, 0.f, 0.f, 0.f);
    int j = beg;
    for (; j + 1 < end; j += 2) {
        int s0 = edgesrc[j];
        int s1 = edgesrc[j + 1];
        float4 v0 = *(const float4*)&T1[(size_t)s0 * F + q * 4];
        float4 v1 = *(const float4*)&T1[(size_t)s1 * F + q * 4];
        acc0.x += v0.x; acc0.y += v0.y; acc0.z += v0.z; acc0.w += v0.w;
        acc1.x += v1.x; acc1.y += v1.y; acc1.z += v1.z; acc1.w += v1.w;
    }
    if (j < end) {
        int s0 = edgesrc[j];
        float4 v0 = *(const float4*)&T1[(size_t)s0 * F + q * 4];
        acc0.x += v0.x; acc0.y += v0.y; acc0.z += v0.z; acc0.w += v0.w;
    }
    acc0.x += acc1.x; acc0.y += acc1.y; acc0.z += acc1.z; acc0.w += acc1.w;
    float4 a = *(const float4*)&A[(size_t)n * F + q * 4];
    a.x = fmaxf(a.x + acc0.x, 0.f);
    a.y = fmaxf(a.y + acc0.y, 0.f);
    a.z = fmaxf(a.z + acc0.z, 0.f);
    a.w = fmaxf(a.w + acc0.w, 0.f);
    *(float4*)&A[(size_t)n * F + q * 4] = a;
}

// ---------------------------------------------------------------------------
// CSR gather of t2 (width 16) + fused log_softmax(t3 + agg). 2-edge unroll.
// ---------------------------------------------------------------------------
__global__ void gather_lsm(const int* __restrict__ rowptr, const int* __restrict__ edgesrc,
                           const float* __restrict__ T3, const float* __restrict__ T2,
                           float* __restrict__ out, int N) {
    int idx = blockIdx.x * blockDim.x + threadIdx.x;
    int n = idx / 4, c = idx % 4;
    if (n >= N) return;
    int beg = rowptr[n], end = rowptr[n + 1];
    float4 acc0 = make_float4(0.f, 0.f, 0.f, 0.f);
    float4 acc1 = make_float4(0.f, 0.f, 0.f, 0.f);
    int j = beg;
    for (; j + 1 < end; j += 2) {
        int s0 = edgesrc[j];
        int s1 = edgesrc[j + 1];
        float4 v0 = *(const float4*)&T2[(size_t)s0 * 16 + c * 4];
        float4 v1 = *(const float4*)&T2[(size_t)s1 * 16 + c * 4];
        acc0.x += v0.x; acc0.y += v0.y; acc0.z += v0.z; acc0.w += v0.w;
        acc1.x += v1.x; acc1.y += v1.y; acc1.z += v1.z; acc1.w += v1.w;
    }
    if (j < end) {
        int s0 = edgesrc[j];
        float4 v0 = *(const float4*)&T2[(size_t)s0 * 16 + c * 4];
        acc0.x += v0.x; acc0.y += v0.y; acc0.z += v0.z; acc0.w += v0.w;
    }
    acc0.x += acc1.x; acc0.y += acc1.y; acc0.z += acc1.z; acc0.w += acc1.w;
    float4 t = *(const float4*)&T3[(size_t)n * 16 + c * 4];
    float4 v = make_float4(t.x + acc0.x, t.y + acc0.y, t.z + acc0.z, t.w + acc0.w);
    float m = fmaxf(fmaxf(v.x, v.y), fmaxf(v.z, v.w));
    for (int d = 1; d < 4; d <<= 1) m = fmaxf(m, __shfl_xor(m, d, 4));
    float s = expf(v.x - m) + expf(v.y - m) + expf(v.z - m) + expf(v.w - m);
    for (int d = 1; d < 4; d <<= 1) s += __shfl_xor(s, d, 4);
    float ls = m + logf(s);
    float4 r = make_float4(v.x - ls, v.y - ls, v.z - ls, v.w - ls);
    *(float4*)&out[(size_t)n * 16 + c * 4] = r;
}

extern "C" void kernel_launch(void* const* d_in, const int* in_sizes, int n_in,
                              void* d_out, int out_size, void* d_ws, size_t ws_size,
                              hipStream_t stream) {
    const float* X      = (const float*)d_in[0];
    const int*   EIDX   = (const int*)d_in[1];
    const float* W1REL  = (const float*)d_in[2];
    const float* W1ROOT = (const float*)d_in[3];
    const float* B1     = (const float*)d_in[4];
    const float* W2REL  = (const float*)d_in[5];
    const float* W2ROOT = (const float*)d_in[6];
    const float* B2     = (const float*)d_in[7];
    float* OUT = (float*)d_out;

    const int N = in_sizes[0] / CIN;   // 100000
    const int E = in_sizes[1] / 2;     // 640000
    const int NB = (N + 1023) / 1024;  // scan blocks (98; merged scan needs <=256)

    char* wsb = (char*)d_ws;
    size_t off = 0;
    auto alloc = [&](size_t bytes) { void* p = wsb + off; off += (bytes + 255) & ~size_t(255); return p; };

    int* srcI     = (int*)alloc((size_t)E * 4);
    int* dstI     = (int*)alloc((size_t)E * 4);
    int* edgesrc  = (int*)alloc((size_t)E * 4);
    int* counts   = (int*)alloc((size_t)N * 4);
    int* rowptr   = (int*)alloc((size_t)(N + 1) * 4);
    int* cursor   = (int*)alloc((size_t)N * 4);
    int* blocksum = (int*)alloc((size_t)NB * 4);
    float* A      = (float*)alloc((size_t)N * CHID * 4);  // t0 -> h (in place)
    float* Bt     = (float*)alloc((size_t)N * CHID * 4);  // t1, then t3|t2
    if (off > ws_size) return;

    float* T3 = Bt;                      // [N,16] (t1 consumed before these are written)
    float* T2 = Bt + (size_t)N * COUT;   // [N,16]

    hipMemsetAsync(counts, 0, (size_t)N * 4, stream);

    convert_hist<<<1024, 256, 0, stream>>>(EIDX, E, srcI, dstI, counts);
    scan_partials<<<NB, 256, 0, stream>>>(counts, N, blocksum);
    scan_apply<<<NB, 256, 0, stream>>>(counts, N, blocksum, NB, rowptr, cursor);
    fill_kernel<<<1024, 256, 0, stream>>>(srcI, dstI, E, cursor, edgesrc);

    // layer 1: A = X@W1root^T + b1 (t0), Bt = X@W1rel^T (t1)
    {
        constexpr int TILE = 16 * 4;   // NSLOT=16, MBLK=4
        int grid = (N + TILE - 1) / TILE;
        gemm_dual48<128, 32, 64, 16, 4><<<grid, 256, 0, stream>>>(X, N, W1ROOT, W1REL, B1, A, Bt);
    }

    // h = relu(t0 + gather(t1))  [in place over A]
    {
        int threads = N * 16;
        gather_relu64<<<(threads + 255) / 256, 256, 0, stream>>>(rowptr, edgesrc, Bt, A, N);
    }

    // layer 2: T3 = h@W2root^T + b2, T2 = h@W2rel^T   (K=64, KT=32, TILE=128)
    {
        constexpr int TILE = 64 * 2;   // NSLOT=64, T=2
        int grid = (N + TILE - 1) / TILE;
        gemm_dual<64, 32, 16, 16, 64, 2><<<grid, 512, 0, stream>>>(A, N, W2ROOT, W2REL, B2, T3, T2);
    }

    // out = log_softmax(t3 + gather(t2))
    {
        int threads = N * 4;
        gather_lsm<<<(threads + 255) / 256, 256, 0, stream>>>(rowptr, edgesrc, T3, T2, OUT, N);
    }
}